// Round 12
// baseline (580.273 us; speedup 1.0000x reference)
//
#include <hip/hip_runtime.h>
#include <stdint.h>

#define N_NODES 50000
#define N_EDGES 800000
#define NFEAT   16
#define EFEAT   8
#define HID     64
#define OUTF    8
#define NMID    2
#define NX      (N_NODES * NFEAT)
#define NPW     16
#define CAP     64
#define PGB     ((N_NODES + 4 * NPW - 1) / (4 * NPW))  // 782 (gemm4/gemmL)
#define PPB     ((N_NODES + 15) / 16)                  // 3125 (prop + propg)
#define NWB     ((N_NODES + 3) / 4)                    // 12500 (wave-per-node)

typedef unsigned short ushort_t;
typedef unsigned int   uint_t;
typedef unsigned long long ull_t;
typedef __bf16 bf16x8 __attribute__((ext_vector_type(8)));
typedef float  f32x4  __attribute__((ext_vector_type(4)));

__device__ __forceinline__ float b2f(ushort_t u) {
    return __uint_as_float(((uint_t)u) << 16);
}
__device__ __forceinline__ ushort_t f2b(float f) {
    uint_t u = __float_as_uint(f);
    return (ushort_t)((u + 0x7fffu + ((u >> 16) & 1u)) >> 16);
}
__device__ __forceinline__ float h2f(ushort_t u) {
    union { ushort_t u; _Float16 h; } c; c.u = u; return (float)c.h;
}
__device__ __forceinline__ ushort_t f2h(float f) {
    union { ushort_t u; _Float16 h; } c; c.h = (_Float16)f; return c.u;
}

// ---------- edge MLP (1 edge/thread, vectorized LDS) + x->bf16 + 4B id scatter ----------
__global__ __launch_bounds__(256) void edge_mlp_kernel(
    const float* __restrict__ ea, const float* __restrict__ x,
    const int* __restrict__ ei,
    const float* __restrict__ W1, const float* __restrict__ b1,
    const float* __restrict__ W2, const float* __restrict__ b2,
    ushort_t* __restrict__ xb, float* __restrict__ ew,
    int* __restrict__ cnts, uint_t* __restrict__ bucket)
{
    __shared__ __align__(16) float W1t[EFEAT * HID];   // transposed: [j][i]
    __shared__ __align__(8)  float2 b1w2[HID];
    __shared__ float b2s;
    int tid = threadIdx.x;
    for (int idx = tid; idx < EFEAT * HID; idx += 256) {
        int j = idx >> 3, i = idx & 7;
        W1t[idx] = W1[i * HID + j];
    }
    if (tid < HID) b1w2[tid] = make_float2(b1[tid], W2[tid]);
    if (tid == 0) b2s = b2[0];
    __syncthreads();

    int e = blockIdx.x * 256 + tid;
    if (e >= N_EDGES) return;

    xb[e] = f2b(x[e]);

    float4 v0 = ((const float4*)ea)[2 * e];
    float4 v1 = ((const float4*)ea)[2 * e + 1];

    float acc = b2s;
    #pragma unroll 2
    for (int j = 0; j < HID; ++j) {
        float4 wa = *(const float4*)&W1t[j * 8];
        float4 wb = *(const float4*)&W1t[j * 8 + 4];
        float2 bw = b1w2[j];
        float h = bw.x;
        h = fmaf(v0.x, wa.x, h); h = fmaf(v0.y, wa.y, h);
        h = fmaf(v0.z, wa.z, h); h = fmaf(v0.w, wa.w, h);
        h = fmaf(v1.x, wb.x, h); h = fmaf(v1.y, wb.y, h);
        h = fmaf(v1.z, wb.z, h); h = fmaf(v1.w, wb.w, h);
        acc = fmaf(fmaxf(h, 0.f), bw.y, acc);
    }
    ew[e] = acc;

    int d = ei[N_EDGES + e];
    int pos = atomicAdd(&cnts[d], 1);
    if (pos < CAP)
        bucket[(size_t)d * CAP + pos] = (uint_t)e;
}

// ---------- deg (fp32-exact) -> dinv, wave per node ----------
__global__ __launch_bounds__(256) void degdinv_kernel(
    int* __restrict__ cnts, const uint_t* __restrict__ bucket,
    const float* __restrict__ ew, float* __restrict__ dinv)
{
    int tid = threadIdx.x;
    int n = blockIdx.x * 4 + (tid >> 6);
    int lane = tid & 63;
    if (n >= N_NODES) return;
    int c = cnts[n]; if (c > CAP) c = CAP;
    float w = 0.f;
    if (lane < c)
        w = ew[bucket[(size_t)n * CAP + lane]];
    #pragma unroll
    for (int o = 32; o; o >>= 1) w += __shfl_down(w, o, 64);
    if (lane == 0) {
        cnts[n] = c;
        dinv[n] = (w > 0.f) ? (1.f / sqrtf(w)) : 0.f;
    }
}

// ---------- rescale: edge-id -> (fp16 norm << 16 | u16 src), in place ----------
__global__ __launch_bounds__(256) void rescale_kernel(
    const int* __restrict__ cnts, const float* __restrict__ dinv,
    const float* __restrict__ ew, const int* __restrict__ ei,
    uint_t* __restrict__ bucket)
{
    int tid = threadIdx.x;
    int n = blockIdx.x * 4 + (tid >> 6);
    int lane = tid & 63;
    if (n >= N_NODES) return;
    int c = cnts[n];
    float dn = dinv[n];
    if (lane < c) {
        uint_t e = bucket[(size_t)n * CAP + lane];
        int s = ei[e];
        float nv = dinv[s] * ew[e] * dn;
        nv = fminf(fmaxf(nv, -60000.f), 60000.f);
        bucket[(size_t)n * CAP + lane] = (((uint_t)f2h(nv)) << 16) | (uint_t)s;
    }
}

// ---------- gather macros (4 nodes/wave, 4B entries) ----------
#define GATHER_PROLOG(WROW)                                                          \
    int cv = (lane < 4) ? cnts[nb + lane] : 0;                                       \
    int c0 = __builtin_amdgcn_readlane(cv, 0);                                       \
    int c1 = __builtin_amdgcn_readlane(cv, 1);                                       \
    int c2 = __builtin_amdgcn_readlane(cv, 2);                                       \
    int c3 = __builtin_amdgcn_readlane(cv, 3);                                       \
    uint_t p0 = 0, p1 = 0, p2 = 0, p3 = 0;                                           \
    if (lane < c0) p0 = bucket[(size_t)(nb + 0) * CAP + lane];                       \
    if (lane < c1) p1 = bucket[(size_t)(nb + 1) * CAP + lane];                       \
    if (lane < c2) p2 = bucket[(size_t)(nb + 2) * CAP + lane];                       \
    if (lane < c3) p3 = bucket[(size_t)(nb + 3) * CAP + lane];

#define GATHER64_BODY()                                                              \
    float s[4][4];                                                                   \
    _Pragma("unroll")                                                                \
    for (int n = 0; n < 4; ++n) {                                                    \
        _Pragma("unroll")                                                            \
        for (int k = 0; k < 4; ++k) s[n][k] = 0.f;                                   \
    }                                                                                \
    int cq0 = c0 & ~3, cq1 = c1 & ~3, cq2 = c2 & ~3, cq3 = c3 & ~3;                  \
    int cqm = max(max(cq0, cq1), max(cq2, cq3));                                     \
    for (int j = 0; j < cqm; j += 4) {                                               \
        GAT4(p0, cq0, 0) GAT4(p1, cq1, 1) GAT4(p2, cq2, 2) GAT4(p3, cq3, 3)          \
    }                                                                                \
    TAILG(p0, cq0, c0, 0) TAILG(p1, cq1, c1, 1)                                      \
    TAILG(p2, cq2, c2, 2) TAILG(p3, cq3, c3, 3)

#define GAT4(pN, cqN, n)                                                             \
    if (j < cqN) {                                                                   \
        _Pragma("unroll")                                                            \
        for (int k = 0; k < 4; ++k) {                                                \
            int pe = __builtin_amdgcn_readlane((int)pN, j + k);                      \
            float nv = h2f((ushort_t)(((uint_t)pe) >> 16));                          \
            float h = b2f(gsrc[(size_t)(pe & 0xffff) * 64 + lane]);                  \
            s[n][k] = fmaf(h, nv, s[n][k]);                                          \
        }                                                                            \
    }
#define TAILG(pN, cqN, cN, n)                                                        \
    for (int j = cqN; j < cN; ++j) {                                                 \
        int pe = __builtin_amdgcn_readlane((int)pN, j);                              \
        float nv = h2f((ushort_t)(((uint_t)pe) >> 16));                              \
        float h = b2f(gsrc[(size_t)(pe & 0xffff) * 64 + lane]);                      \
        s[n][0] = fmaf(h, nv, s[n][0]);                                              \
    }

// ---------- pure propagation: widths 64 and 16 ----------
template<int W>
__global__ __launch_bounds__(256, 6) void prop_kernel(
    const ushort_t* __restrict__ gsrc, ushort_t* __restrict__ gout,
    const int* __restrict__ cnts, const uint_t* __restrict__ bucket)
{
    int tid = threadIdx.x;
    int wv = tid >> 6, lane = tid & 63;
    int nb = (blockIdx.x * 4 + wv) * 4;
    if (nb >= N_NODES) return;

    GATHER_PROLOG(W)

    if (W == 64) {
        GATHER64_BODY()
        #pragma unroll
        for (int n = 0; n < 4; ++n) {
            float v = (s[n][0] + s[n][1]) + (s[n][2] + s[n][3]);
            gout[(size_t)(nb + n) * 64 + lane] = f2b(v);
        }
    } else {
        const int il = lane & 15;
        const int quad = lane >> 4;
        #define PROC16(pN, cN, n)                                                    \
            {                                                                        \
                float s = 0.f;                                                       \
                for (int j = 0; j < cN; j += 4) {                                    \
                    int j4 = j + quad;                                               \
                    int pw = __shfl((int)pN, j4 & 63, 64);                           \
                    bool valid = j4 < cN;                                            \
                    int src = valid ? (pw & 0xffff) : 0;                             \
                    float nv = valid ? h2f((ushort_t)(((uint_t)pw) >> 16)) : 0.f;    \
                    float h = b2f(gsrc[(size_t)src * 16 + il]);                      \
                    s = fmaf(h, nv, s);                                              \
                }                                                                    \
                s += __shfl_xor(s, 16, 64);                                          \
                s += __shfl_xor(s, 32, 64);                                          \
                if (lane < 16) gout[(size_t)(nb + n) * 16 + lane] = f2b(s);          \
            }
        PROC16(p0, c0, 0)
        PROC16(p1, c1, 1)
        PROC16(p2, c2, 2)
        PROC16(p3, c3, 3)
        #undef PROC16
    }
}

// ---------- fused 3rd-prop + 4-source MFMA GEMM (mid layers, 64->64, relu) ----------
// Block = 4 waves x 4 nodes = 16 nodes. g3 rows live only in LDS.
__global__ __launch_bounds__(256, 4) void propg_kernel(
    const ushort_t* __restrict__ g2in,   // gather source = g2 (also gemm s2)
    const ushort_t* __restrict__ s0,     // cin
    const ushort_t* __restrict__ s1,     // g1
    const float* __restrict__ Wg,        // (4, 64, 64) fp32
    const float* __restrict__ bias,
    ushort_t* __restrict__ outb,
    const int* __restrict__ cnts, const uint_t* __restrict__ bucket)
{
    __shared__ __align__(16) ushort_t Bp[8 * 4 * 512];
    __shared__ __align__(16) ushort_t gt[16 * 72];   // 16 rows, stride 72 (pad 8)

    int tid = threadIdx.x;
    for (int idx = tid; idx < 8 * 4 * 512; idx += 256) {
        int f = idx >> 9;
        int ch = f >> 2, nt = f & 3;
        int l = (idx >> 3) & 63, j = idx & 7;
        int kk = ((l >> 4) << 3) + j;
        int n = nt * 16 + (l & 15);
        int widx = ch >> 1, krow = ((ch & 1) << 5) + kk;
        Bp[idx] = f2b(Wg[((size_t)widx * 64 + krow) * 64 + n]);
    }

    int wv = tid >> 6, lane = tid & 63;
    int nb = blockIdx.x * 16 + wv * 4;   // N_NODES % 16 == 0, all blocks full
    const ushort_t* gsrc = g2in;

    GATHER_PROLOG(64)
    GATHER64_BODY()
    #pragma unroll
    for (int n = 0; n < 4; ++n) {
        float v = (s[n][0] + s[n][1]) + (s[n][2] + s[n][3]);
        gt[(wv * 4 + n) * 72 + lane] = f2b(v);
    }
    __syncthreads();

    // MFMA phase: this wave computes cols [wv*16, wv*16+16)
    int m = lane & 15, quad = lane >> 4;
    bf16x8 a[8];
    #pragma unroll
    for (int ch = 0; ch < 8; ++ch) {
        int widx = ch >> 1, kh = ch & 1;
        if (widx == 0)
            a[ch] = *(const bf16x8*)(s0 + (size_t)(blockIdx.x * 16 + m) * 64 + kh * 32 + quad * 8);
        else if (widx == 1)
            a[ch] = *(const bf16x8*)(s1 + (size_t)(blockIdx.x * 16 + m) * 64 + kh * 32 + quad * 8);
        else if (widx == 2)
            a[ch] = *(const bf16x8*)(g2in + (size_t)(blockIdx.x * 16 + m) * 64 + kh * 32 + quad * 8);
        else
            a[ch] = *(const bf16x8*)&gt[m * 72 + kh * 32 + quad * 8];
    }

    float bv = bias[wv * 16 + m];
    f32x4 c = {bv, bv, bv, bv};
    #pragma unroll
    for (int ch = 0; ch < 8; ++ch) {
        bf16x8 b = *(const bf16x8*)&Bp[((ch * 4 + wv) * 64 + lane) * 8];
        c = __builtin_amdgcn_mfma_f32_16x16x32_bf16(a[ch], b, c, 0, 0, 0);
    }
    #pragma unroll
    for (int r = 0; r < 4; ++r) {
        int row = blockIdx.x * 16 + quad * 4 + r;
        outb[(size_t)row * 64 + wv * 16 + m] = f2b(fmaxf(c[r], 0.f));
    }
}

// ---------- width-8 Horner propagation ----------
template<int F32OUT>
__global__ __launch_bounds__(256, 8) void prop8_kernel(
    const ushort_t* __restrict__ gsrc, int GS, int GO,
    const ushort_t* __restrict__ add, int AS, int AO,
    ushort_t* __restrict__ outb, float* __restrict__ outf,
    const int* __restrict__ cnts, const uint_t* __restrict__ bucket)
{
    int tid = threadIdx.x;
    int wv = tid >> 6, lane = tid & 63;
    int nb = (blockIdx.x * 4 + wv) * 4;
    if (nb >= N_NODES) return;
    const int oct = lane >> 3, il = lane & 7;

    GATHER_PROLOG(8)

    #define PROC8(pN, cN, n)                                                         \
        {                                                                            \
            float s = 0.f;                                                           \
            for (int j = 0; j < cN; j += 8) {                                        \
                int jo = j + oct;                                                    \
                int pw = __shfl((int)pN, jo & 63, 64);                               \
                bool valid = jo < cN;                                                \
                int src = valid ? (pw & 0xffff) : 0;                                 \
                float nv = valid ? h2f((ushort_t)(((uint_t)pw) >> 16)) : 0.f;        \
                float h = b2f(gsrc[(size_t)src * GS + GO + il]);                     \
                s = fmaf(h, nv, s);                                                  \
            }                                                                        \
            s += __shfl_xor(s, 8, 64);                                               \
            s += __shfl_xor(s, 16, 64);                                              \
            s += __shfl_xor(s, 32, 64);                                              \
            if (lane < 8) {                                                          \
                float v = s + b2f(add[(size_t)(nb + n) * AS + AO + lane]);           \
                if (F32OUT) outf[(size_t)(nb + n) * 8 + lane] = v;                   \
                else        outb[(size_t)(nb + n) * 8 + lane] = f2b(v);              \
            }                                                                        \
        }
    PROC8(p0, c0, 0)
    PROC8(p1, c1, 1)
    PROC8(p2, c2, 2)
    PROC8(p3, c3, 3)
    #undef PROC8
}

// ---------- dense 4-source MFMA GEMM (layer 0 only, SRCW=16) ----------
template<int SRCW, int COUT, int ACT>
__global__ __launch_bounds__(256, 4) void gemm4_kernel(
    const ushort_t* __restrict__ s0, const ushort_t* __restrict__ s1,
    const ushort_t* __restrict__ s2, const ushort_t* __restrict__ s3,
    const float* __restrict__ Wg, const float* __restrict__ bias,
    ushort_t* __restrict__ outb)
{
    constexpr int NCH = (SRCW == 16) ? 2 : 8;
    constexpr int NT  = (COUT + 15) / 16;
    __shared__ __align__(16) ushort_t Bp[NCH * NT * 512];

    int tid = threadIdx.x;
    for (int idx = tid; idx < NCH * NT * 512; idx += 256) {
        int f = idx >> 9;
        int l = (idx >> 3) & 63, j = idx & 7;
        int ch = f / NT, nt = f - ch * NT;
        int kk = ((l >> 4) << 3) + j;
        int n = nt * 16 + (l & 15);
        int widx, krow;
        if (SRCW == 16) { widx = 2 * ch + (kk >> 4); krow = kk & 15; }
        else            { widx = ch >> 1;            krow = ((ch & 1) << 5) + kk; }
        float v = (n < COUT) ? Wg[((size_t)widx * SRCW + krow) * COUT + n] : 0.f;
        Bp[idx] = f2b(v);
    }
    __syncthreads();

    int wv = tid >> 6, lane = tid & 63;
    int node_base = (blockIdx.x * 4 + wv) * NPW;
    if (node_base >= N_NODES) return;
    int m = lane & 15, quad = lane >> 4;

    const ushort_t* srcs[4] = {s0, s1, s2, s3};
    bf16x8 a[NCH];
    #pragma unroll
    for (int ch = 0; ch < NCH; ++ch) {
        const ushort_t* sp;
        size_t off;
        if (SRCW == 16) {
            sp = (quad < 2) ? srcs[2 * ch] : srcs[2 * ch + 1];
            off = (size_t)(node_base + m) * 16 + (quad & 1) * 8;
        } else {
            sp = srcs[ch >> 1];
            off = (size_t)(node_base + m) * 64 + ((ch & 1) << 5) + quad * 8;
        }
        a[ch] = *(const bf16x8*)(sp + off);
    }

    #pragma unroll
    for (int nt = 0; nt < NT; ++nt) {
        float bv = bias[(nt * 16 + m) & (COUT - 1)];
        f32x4 c = {bv, bv, bv, bv};
        #pragma unroll
        for (int ch = 0; ch < NCH; ++ch) {
            bf16x8 b = *(const bf16x8*)&Bp[((ch * NT + nt) * 64 + lane) * 8];
            c = __builtin_amdgcn_mfma_f32_16x16x32_bf16(a[ch], b, c, 0, 0, 0);
        }
        #pragma unroll
        for (int r = 0; r < 4; ++r) {
            int row = node_base + quad * 4 + r;
            float v = ACT ? fmaxf(c[r], 0.f) : c[r];
            outb[(size_t)row * COUT + nt * 16 + m] = f2b(v);
        }
    }
}

// ---------- last-layer Z pack ----------
__global__ __launch_bounds__(256, 4) void gemmL_kernel(
    const ushort_t* __restrict__ src,
    const float* __restrict__ Wl, const float* __restrict__ bl,
    ushort_t* __restrict__ Z)
{
    __shared__ __align__(16) ushort_t Bp[2 * 2 * 512];

    int tid = threadIdx.x;
    for (int idx = tid; idx < 2048; idx += 256) {
        int f = idx >> 9;
        int ch = f >> 1, nt = f & 1;
        int l = (idx >> 3) & 63, j = idx & 7;
        int kg = ch * 32 + ((l >> 4) << 3) + j;
        int n = nt * 16 + (l & 15);
        int widx = n >> 3, col = n & 7;
        Bp[idx] = f2b(Wl[((size_t)widx * 64 + kg) * 8 + col]);
    }
    __syncthreads();

    int wv = tid >> 6, lane = tid & 63;
    int node_base = (blockIdx.x * 4 + wv) * NPW;
    if (node_base >= N_NODES) return;
    int m = lane & 15, quad = lane >> 4;

    bf16x8 a[2];
    #pragma unroll
    for (int ch = 0; ch < 2; ++ch)
        a[ch] = *(const bf16x8*)(src + (size_t)(node_base + m) * 64 + ch * 32 + quad * 8);

    #pragma unroll
    for (int nt = 0; nt < 2; ++nt) {
        int n = nt * 16 + m;
        float bv = (n < 8) ? bl[n] : 0.f;
        f32x4 c = {bv, bv, bv, bv};
        #pragma unroll
        for (int ch = 0; ch < 2; ++ch) {
            bf16x8 b = *(const bf16x8*)&Bp[((ch * 2 + nt) * 64 + lane) * 8];
            c = __builtin_amdgcn_mfma_f32_16x16x32_bf16(a[ch], b, c, 0, 0, 0);
        }
        #pragma unroll
        for (int r = 0; r < 4; ++r) {
            int row = node_base + quad * 4 + r;
            Z[(size_t)row * 32 + n] = f2b(c[r]);
        }
    }
}

extern "C" void kernel_launch(void* const* d_in, const int* in_sizes, int n_in,
                              void* d_out, int out_size, void* d_ws, size_t ws_size,
                              hipStream_t stream)
{
    const float* x  = (const float*)d_in[0];
    const int*   ei = (const int*)d_in[1];
    const float* ea = (const float*)d_in[2];
    const float* W1 = (const float*)d_in[3];
    const float* b1 = (const float*)d_in[4];
    const float* W2 = (const float*)d_in[5];
    const float* b2 = (const float*)d_in[6];
    const float* Wf = (const float*)d_in[7];
    const float* bf = (const float*)d_in[8];
    const float* Wm = (const float*)d_in[9];
    const float* bm = (const float*)d_in[10];
    const float* Wl = (const float*)d_in[11];
    const float* bl = (const float*)d_in[12];

    char* ws = (char*)d_ws;
    size_t off = 0;
    auto take = [&](size_t bytes) -> char* {
        char* p = ws + off;
        off = (off + bytes + 255) & ~(size_t)255;
        return p;
    };
    int*      cnts   = (int*)take((size_t)N_NODES * 4);
    float*    dinv   = (float*)take((size_t)N_NODES * 4);
    float*    ew     = (float*)take((size_t)N_EDGES * 4);
    uint_t*   bucket = (uint_t*)take((size_t)N_NODES * CAP * 4);
    ushort_t* xb     = (ushort_t*)take((size_t)NX * 2 + 256);
    ushort_t* g1     = (ushort_t*)take((size_t)N_NODES * HID * 2 + 256);
    ushort_t* g2     = (ushort_t*)take((size_t)N_NODES * HID * 2 + 256);
    ushort_t* g3     = (ushort_t*)take((size_t)N_NODES * HID * 2 + 256);
    ushort_t* curA   = (ushort_t*)take((size_t)N_NODES * HID * 2 + 256);
    ushort_t* curB   = (ushort_t*)take((size_t)N_NODES * HID * 2 + 256);
    ushort_t* Z      = (ushort_t*)take((size_t)N_NODES * 32 * 2 + 256);
    ushort_t* t8a    = (ushort_t*)take((size_t)N_NODES * 8 * 2 + 256);
    ushort_t* t8b    = (ushort_t*)take((size_t)N_NODES * 8 * 2 + 256);

    hipMemsetAsync(cnts, 0, (size_t)N_NODES * 4, stream);

    const int EB = (N_EDGES + 255) / 256;   // 3125

    edge_mlp_kernel<<<EB, 256, 0, stream>>>(ea, x, ei, W1, b1, W2, b2, xb, ew, cnts, bucket);
    degdinv_kernel<<<NWB, 256, 0, stream>>>(cnts, bucket, ew, dinv);
    rescale_kernel<<<NWB, 256, 0, stream>>>(cnts, dinv, ew, ei, bucket);

    // ---- layer 0: 16 -> 64, relu ----
    prop_kernel<NFEAT><<<PPB, 256, 0, stream>>>(xb, g1, cnts, bucket);
    prop_kernel<NFEAT><<<PPB, 256, 0, stream>>>(g1, g2, cnts, bucket);
    prop_kernel<NFEAT><<<PPB, 256, 0, stream>>>(g2, g3, cnts, bucket);
    gemm4_kernel<NFEAT, HID, 1><<<PGB, 256, 0, stream>>>(
        xb, g1, g2, g3, Wf, bf, curA);

    // ---- mid layers: 64 -> 64, relu; 3rd prop fused with gemm ----
    ushort_t* cin = curA;
    ushort_t* cot = curB;
    for (int L = 0; L < NMID; ++L) {
        prop_kernel<HID><<<PPB, 256, 0, stream>>>(cin, g1, cnts, bucket);
        prop_kernel<HID><<<PPB, 256, 0, stream>>>(g1, g2, cnts, bucket);
        propg_kernel<<<PPB, 256, 0, stream>>>(
            g2, cin, g1, Wm + (size_t)L * 4 * HID * HID, bm + L * HID, cot, cnts, bucket);
        ushort_t* t = cin; cin = cot; cot = t;
    }

    // ---- last layer (Horner) ----
    gemmL_kernel<<<PGB, 256, 0, stream>>>(cin, Wl, bl, Z);
    prop8_kernel<0><<<PPB, 256, 0, stream>>>(Z, 32, 24, Z, 32, 16, t8a, nullptr, cnts, bucket);
    prop8_kernel<0><<<PPB, 256, 0, stream>>>(t8a, 8, 0, Z, 32, 8, t8b, nullptr, cnts, bucket);
    prop8_kernel<1><<<PPB, 256, 0, stream>>>(t8b, 8, 0, Z, 32, 0, nullptr, (float*)d_out, cnts, bucket);
}

// Round 13
// 458.759 us; speedup vs baseline: 1.2649x; 1.2649x over previous
//
#include <hip/hip_runtime.h>
#include <stdint.h>

#define N_NODES 50000
#define N_EDGES 800000
#define NFEAT   16
#define EFEAT   8
#define HID     64
#define OUTF    8
#define NMID    2
#define NX      (N_NODES * NFEAT)
#define NPW     16
#define CAP     64
#define PGB     ((N_NODES + 4 * NPW - 1) / (4 * NPW))  // 782 (gemm4/gemmL)
#define PPB     ((N_NODES + 15) / 16)                  // 3125 (prop)
#define NWB     ((N_NODES + 3) / 4)                    // 12500 (wave-per-node)

typedef unsigned short ushort_t;
typedef unsigned int   uint_t;
typedef unsigned long long ull_t;
typedef __bf16 bf16x8 __attribute__((ext_vector_type(8)));
typedef float  f32x4  __attribute__((ext_vector_type(4)));

__device__ __forceinline__ float b2f(ushort_t u) {
    return __uint_as_float(((uint_t)u) << 16);
}
__device__ __forceinline__ ushort_t f2b(float f) {
    uint_t u = __float_as_uint(f);
    return (ushort_t)((u + 0x7fffu + ((u >> 16) & 1u)) >> 16);
}
__device__ __forceinline__ float h2f(ushort_t u) {
    union { ushort_t u; _Float16 h; } c; c.u = u; return (float)c.h;
}
__device__ __forceinline__ ushort_t f2h(float f) {
    union { ushort_t u; _Float16 h; } c; c.h = (_Float16)f; return c.u;
}

// ---------- edge MLP (1 edge/thread, vectorized LDS) + x->bf16 + 4B id scatter ----------
__global__ __launch_bounds__(256) void edge_mlp_kernel(
    const float* __restrict__ ea, const float* __restrict__ x,
    const int* __restrict__ ei,
    const float* __restrict__ W1, const float* __restrict__ b1,
    const float* __restrict__ W2, const float* __restrict__ b2,
    ushort_t* __restrict__ xb, float* __restrict__ ew,
    int* __restrict__ cnts, uint_t* __restrict__ bucket)
{
    __shared__ __align__(16) float W1t[EFEAT * HID];   // transposed: [j][i]
    __shared__ __align__(8)  float2 b1w2[HID];
    __shared__ float b2s;
    int tid = threadIdx.x;
    for (int idx = tid; idx < EFEAT * HID; idx += 256) {
        int j = idx >> 3, i = idx & 7;
        W1t[idx] = W1[i * HID + j];
    }
    if (tid < HID) b1w2[tid] = make_float2(b1[tid], W2[tid]);
    if (tid == 0) b2s = b2[0];
    __syncthreads();

    int e = blockIdx.x * 256 + tid;
    if (e >= N_EDGES) return;

    xb[e] = f2b(x[e]);

    float4 v0 = ((const float4*)ea)[2 * e];
    float4 v1 = ((const float4*)ea)[2 * e + 1];

    float acc = b2s;
    #pragma unroll 2
    for (int j = 0; j < HID; ++j) {
        float4 wa = *(const float4*)&W1t[j * 8];
        float4 wb = *(const float4*)&W1t[j * 8 + 4];
        float2 bw = b1w2[j];
        float h = bw.x;
        h = fmaf(v0.x, wa.x, h); h = fmaf(v0.y, wa.y, h);
        h = fmaf(v0.z, wa.z, h); h = fmaf(v0.w, wa.w, h);
        h = fmaf(v1.x, wb.x, h); h = fmaf(v1.y, wb.y, h);
        h = fmaf(v1.z, wb.z, h); h = fmaf(v1.w, wb.w, h);
        acc = fmaf(fmaxf(h, 0.f), bw.y, acc);
    }
    ew[e] = acc;

    int d = ei[N_EDGES + e];
    int pos = atomicAdd(&cnts[d], 1);
    if (pos < CAP)
        bucket[(size_t)d * CAP + pos] = (uint_t)e;
}

// ---------- deg (fp32-exact) -> dinv, wave per node ----------
__global__ __launch_bounds__(256) void degdinv_kernel(
    int* __restrict__ cnts, const uint_t* __restrict__ bucket,
    const float* __restrict__ ew, float* __restrict__ dinv)
{
    int tid = threadIdx.x;
    int n = blockIdx.x * 4 + (tid >> 6);
    int lane = tid & 63;
    if (n >= N_NODES) return;
    int c = cnts[n]; if (c > CAP) c = CAP;
    float w = 0.f;
    if (lane < c)
        w = ew[bucket[(size_t)n * CAP + lane]];
    #pragma unroll
    for (int o = 32; o; o >>= 1) w += __shfl_down(w, o, 64);
    if (lane == 0) {
        cnts[n] = c;
        dinv[n] = (w > 0.f) ? (1.f / sqrtf(w)) : 0.f;
    }
}

// ---------- rescale: edge-id -> (fp16 norm << 16 | u16 src), in place ----------
__global__ __launch_bounds__(256) void rescale_kernel(
    const int* __restrict__ cnts, const float* __restrict__ dinv,
    const float* __restrict__ ew, const int* __restrict__ ei,
    uint_t* __restrict__ bucket)
{
    int tid = threadIdx.x;
    int n = blockIdx.x * 4 + (tid >> 6);
    int lane = tid & 63;
    if (n >= N_NODES) return;
    int c = cnts[n];
    float dn = dinv[n];
    if (lane < c) {
        uint_t e = bucket[(size_t)n * CAP + lane];
        int s = ei[e];
        float nv = dinv[s] * ew[e] * dn;
        nv = fminf(fmaxf(nv, -60000.f), 60000.f);
        bucket[(size_t)n * CAP + lane] = (((uint_t)f2h(nv)) << 16) | (uint_t)s;
    }
}

// ---------- pure propagation: 4 nodes/wave (widths 64 and 16), 4B entries ----------
template<int W>
__global__ __launch_bounds__(256, 6) void prop_kernel(
    const ushort_t* __restrict__ gsrc, ushort_t* __restrict__ gout,
    const int* __restrict__ cnts, const uint_t* __restrict__ bucket)
{
    int tid = threadIdx.x;
    int wv = tid >> 6, lane = tid & 63;
    int nb = (blockIdx.x * 4 + wv) * 4;
    if (nb >= N_NODES) return;

    int cv = (lane < 4) ? cnts[nb + lane] : 0;
    int c0 = __builtin_amdgcn_readlane(cv, 0);
    int c1 = __builtin_amdgcn_readlane(cv, 1);
    int c2 = __builtin_amdgcn_readlane(cv, 2);
    int c3 = __builtin_amdgcn_readlane(cv, 3);

    uint_t p0 = 0, p1 = 0, p2 = 0, p3 = 0;
    if (lane < c0) p0 = bucket[(size_t)(nb + 0) * CAP + lane];
    if (lane < c1) p1 = bucket[(size_t)(nb + 1) * CAP + lane];
    if (lane < c2) p2 = bucket[(size_t)(nb + 2) * CAP + lane];
    if (lane < c3) p3 = bucket[(size_t)(nb + 3) * CAP + lane];

    if (W == 64) {
        float s[4][4];
        #pragma unroll
        for (int n = 0; n < 4; ++n)
            #pragma unroll
            for (int k = 0; k < 4; ++k) s[n][k] = 0.f;

        int cq0 = c0 & ~3, cq1 = c1 & ~3, cq2 = c2 & ~3, cq3 = c3 & ~3;
        int cqm = max(max(cq0, cq1), max(cq2, cq3));

        for (int j = 0; j < cqm; j += 4) {
            #define GAT4(pN, cqN, n)                                                 \
                if (j < cqN) {                                                       \
                    _Pragma("unroll")                                                \
                    for (int k = 0; k < 4; ++k) {                                    \
                        int pe = __builtin_amdgcn_readlane((int)pN, j + k);          \
                        float nv = h2f((ushort_t)(((uint_t)pe) >> 16));              \
                        float h = b2f(gsrc[(size_t)(pe & 0xffff) * 64 + lane]);      \
                        s[n][k] = fmaf(h, nv, s[n][k]);                              \
                    }                                                                \
                }
            GAT4(p0, cq0, 0)
            GAT4(p1, cq1, 1)
            GAT4(p2, cq2, 2)
            GAT4(p3, cq3, 3)
            #undef GAT4
        }
        #define TAILG(pN, cqN, cN, n)                                                \
            for (int j = cqN; j < cN; ++j) {                                         \
                int pe = __builtin_amdgcn_readlane((int)pN, j);                      \
                float nv = h2f((ushort_t)(((uint_t)pe) >> 16));                      \
                float h = b2f(gsrc[(size_t)(pe & 0xffff) * 64 + lane]);              \
                s[n][0] = fmaf(h, nv, s[n][0]);                                      \
            }
        TAILG(p0, cq0, c0, 0)
        TAILG(p1, cq1, c1, 1)
        TAILG(p2, cq2, c2, 2)
        TAILG(p3, cq3, c3, 3)
        #undef TAILG

        #pragma unroll
        for (int n = 0; n < 4; ++n) {
            float v = (s[n][0] + s[n][1]) + (s[n][2] + s[n][3]);
            gout[(size_t)(nb + n) * 64 + lane] = f2b(v);
        }
    } else {
        const int il = lane & 15;
        const int quad = lane >> 4;
        #define PROC16(pN, cN, n)                                                    \
            {                                                                        \
                float s = 0.f;                                                       \
                for (int j = 0; j < cN; j += 4) {                                    \
                    int j4 = j + quad;                                               \
                    int pw = __shfl((int)pN, j4 & 63, 64);                           \
                    bool valid = j4 < cN;                                            \
                    int src = valid ? (pw & 0xffff) : 0;                             \
                    float nv = valid ? h2f((ushort_t)(((uint_t)pw) >> 16)) : 0.f;    \
                    float h = b2f(gsrc[(size_t)src * 16 + il]);                      \
                    s = fmaf(h, nv, s);                                              \
                }                                                                    \
                s += __shfl_xor(s, 16, 64);                                          \
                s += __shfl_xor(s, 32, 64);                                          \
                if (lane < 16) gout[(size_t)(nb + n) * 16 + lane] = f2b(s);          \
            }
        PROC16(p0, c0, 0)
        PROC16(p1, c1, 1)
        PROC16(p2, c2, 2)
        PROC16(p3, c3, 3)
        #undef PROC16
    }
}

// ---------- width-8 Horner propagation: out[n] = A·gsrc + add  (octet per edge) ----------
template<int F32OUT>
__global__ __launch_bounds__(256, 8) void prop8_kernel(
    const ushort_t* __restrict__ gsrc, int GS, int GO,
    const ushort_t* __restrict__ add, int AS, int AO,
    ushort_t* __restrict__ outb, float* __restrict__ outf,
    const int* __restrict__ cnts, const uint_t* __restrict__ bucket)
{
    int tid = threadIdx.x;
    int wv = tid >> 6, lane = tid & 63;
    int nb = (blockIdx.x * 4 + wv) * 4;
    if (nb >= N_NODES) return;
    const int oct = lane >> 3, il = lane & 7;

    int cv = (lane < 4) ? cnts[nb + lane] : 0;
    int c0 = __builtin_amdgcn_readlane(cv, 0);
    int c1 = __builtin_amdgcn_readlane(cv, 1);
    int c2 = __builtin_amdgcn_readlane(cv, 2);
    int c3 = __builtin_amdgcn_readlane(cv, 3);

    uint_t p0 = 0, p1 = 0, p2 = 0, p3 = 0;
    if (lane < c0) p0 = bucket[(size_t)(nb + 0) * CAP + lane];
    if (lane < c1) p1 = bucket[(size_t)(nb + 1) * CAP + lane];
    if (lane < c2) p2 = bucket[(size_t)(nb + 2) * CAP + lane];
    if (lane < c3) p3 = bucket[(size_t)(nb + 3) * CAP + lane];

    #define PROC8(pN, cN, n)                                                         \
        {                                                                            \
            float s = 0.f;                                                           \
            for (int j = 0; j < cN; j += 8) {                                        \
                int jo = j + oct;                                                    \
                int pw = __shfl((int)pN, jo & 63, 64);                               \
                bool valid = jo < cN;                                                \
                int src = valid ? (pw & 0xffff) : 0;                                 \
                float nv = valid ? h2f((ushort_t)(((uint_t)pw) >> 16)) : 0.f;        \
                float h = b2f(gsrc[(size_t)src * GS + GO + il]);                     \
                s = fmaf(h, nv, s);                                                  \
            }                                                                        \
            s += __shfl_xor(s, 8, 64);                                               \
            s += __shfl_xor(s, 16, 64);                                              \
            s += __shfl_xor(s, 32, 64);                                              \
            if (lane < 8) {                                                          \
                float v = s + b2f(add[(size_t)(nb + n) * AS + AO + lane]);           \
                if (F32OUT) outf[(size_t)(nb + n) * 8 + lane] = v;                   \
                else        outb[(size_t)(nb + n) * 8 + lane] = f2b(v);              \
            }                                                                        \
        }
    PROC8(p0, c0, 0)
    PROC8(p1, c1, 1)
    PROC8(p2, c2, 2)
    PROC8(p3, c3, 3)
    #undef PROC8
}

// ---------- dense 4-source MFMA GEMM: out = act(bias + sum_s src_s @ W_s) ----------
template<int SRCW, int COUT, int ACT>
__global__ __launch_bounds__(256, 4) void gemm4_kernel(
    const ushort_t* __restrict__ s0, const ushort_t* __restrict__ s1,
    const ushort_t* __restrict__ s2, const ushort_t* __restrict__ s3,
    const float* __restrict__ Wg,    // (4, SRCW, COUT) fp32
    const float* __restrict__ bias,
    ushort_t* __restrict__ outb)
{
    constexpr int NCH = (SRCW == 16) ? 2 : 8;
    constexpr int NT  = (COUT + 15) / 16;
    __shared__ __align__(16) ushort_t Bp[NCH * NT * 512];

    int tid = threadIdx.x;
    for (int idx = tid; idx < NCH * NT * 512; idx += 256) {
        int f = idx >> 9;
        int l = (idx >> 3) & 63, j = idx & 7;
        int ch = f / NT, nt = f - ch * NT;
        int kk = ((l >> 4) << 3) + j;
        int n = nt * 16 + (l & 15);
        int widx, krow;
        if (SRCW == 16) { widx = 2 * ch + (kk >> 4); krow = kk & 15; }
        else            { widx = ch >> 1;            krow = ((ch & 1) << 5) + kk; }
        float v = (n < COUT) ? Wg[((size_t)widx * SRCW + krow) * COUT + n] : 0.f;
        Bp[idx] = f2b(v);
    }
    __syncthreads();

    int wv = tid >> 6, lane = tid & 63;
    int node_base = (blockIdx.x * 4 + wv) * NPW;
    if (node_base >= N_NODES) return;
    int m = lane & 15, quad = lane >> 4;

    const ushort_t* srcs[4] = {s0, s1, s2, s3};
    bf16x8 a[NCH];
    #pragma unroll
    for (int ch = 0; ch < NCH; ++ch) {
        const ushort_t* sp;
        size_t off;
        if (SRCW == 16) {
            sp = (quad < 2) ? srcs[2 * ch] : srcs[2 * ch + 1];
            off = (size_t)(node_base + m) * 16 + (quad & 1) * 8;
        } else {
            sp = srcs[ch >> 1];
            off = (size_t)(node_base + m) * 64 + ((ch & 1) << 5) + quad * 8;
        }
        a[ch] = *(const bf16x8*)(sp + off);
    }

    #pragma unroll
    for (int nt = 0; nt < NT; ++nt) {
        float bv = bias[(nt * 16 + m) & (COUT - 1)];
        f32x4 c = {bv, bv, bv, bv};
        #pragma unroll
        for (int ch = 0; ch < NCH; ++ch) {
            bf16x8 b = *(const bf16x8*)&Bp[((ch * NT + nt) * 64 + lane) * 8];
            c = __builtin_amdgcn_mfma_f32_16x16x32_bf16(a[ch], b, c, 0, 0, 0);
        }
        #pragma unroll
        for (int r = 0; r < 4; ++r) {
            int row = node_base + quad * 4 + r;
            float v = ACT ? fmaxf(c[r], 0.f) : c[r];
            outb[(size_t)row * COUT + nt * 16 + m] = f2b(v);
        }
    }
}

// ---------- last-layer Z pack: Z[n][4*8] = [cin@Wl0 + bl | cin@Wl1 | cin@Wl2 | cin@Wl3] ----------
__global__ __launch_bounds__(256, 4) void gemmL_kernel(
    const ushort_t* __restrict__ src,
    const float* __restrict__ Wl, const float* __restrict__ bl,
    ushort_t* __restrict__ Z)
{
    __shared__ __align__(16) ushort_t Bp[2 * 2 * 512];

    int tid = threadIdx.x;
    for (int idx = tid; idx < 2048; idx += 256) {
        int f = idx >> 9;
        int ch = f >> 1, nt = f & 1;
        int l = (idx >> 3) & 63, j = idx & 7;
        int kg = ch * 32 + ((l >> 4) << 3) + j;
        int n = nt * 16 + (l & 15);
        int widx = n >> 3, col = n & 7;
        Bp[idx] = f2b(Wl[((size_t)widx * 64 + kg) * 8 + col]);
    }
    __syncthreads();

    int wv = tid >> 6, lane = tid & 63;
    int node_base = (blockIdx.x * 4 + wv) * NPW;
    if (node_base >= N_NODES) return;
    int m = lane & 15, quad = lane >> 4;

    bf16x8 a[2];
    #pragma unroll
    for (int ch = 0; ch < 2; ++ch)
        a[ch] = *(const bf16x8*)(src + (size_t)(node_base + m) * 64 + ch * 32 + quad * 8);

    #pragma unroll
    for (int nt = 0; nt < 2; ++nt) {
        int n = nt * 16 + m;
        float bv = (n < 8) ? bl[n] : 0.f;
        f32x4 c = {bv, bv, bv, bv};
        #pragma unroll
        for (int ch = 0; ch < 2; ++ch) {
            bf16x8 b = *(const bf16x8*)&Bp[((ch * 2 + nt) * 64 + lane) * 8];
            c = __builtin_amdgcn_mfma_f32_16x16x32_bf16(a[ch], b, c, 0, 0, 0);
        }
        #pragma unroll
        for (int r = 0; r < 4; ++r) {
            int row = node_base + quad * 4 + r;
            Z[(size_t)row * 32 + n] = f2b(c[r]);
        }
    }
}

extern "C" void kernel_launch(void* const* d_in, const int* in_sizes, int n_in,
                              void* d_out, int out_size, void* d_ws, size_t ws_size,
                              hipStream_t stream)
{
    const float* x  = (const float*)d_in[0];
    const int*   ei = (const int*)d_in[1];
    const float* ea = (const float*)d_in[2];
    const float* W1 = (const float*)d_in[3];
    const float* b1 = (const float*)d_in[4];
    const float* W2 = (const float*)d_in[5];
    const float* b2 = (const float*)d_in[6];
    const float* Wf = (const float*)d_in[7];
    const float* bf = (const float*)d_in[8];
    const float* Wm = (const float*)d_in[9];
    const float* bm = (const float*)d_in[10];
    const float* Wl = (const float*)d_in[11];
    const float* bl = (const float*)d_in[12];

    char* ws = (char*)d_ws;
    size_t off = 0;
    auto take = [&](size_t bytes) -> char* {
        char* p = ws + off;
        off = (off + bytes + 255) & ~(size_t)255;
        return p;
    };
    int*      cnts   = (int*)take((size_t)N_NODES * 4);
    float*    dinv   = (float*)take((size_t)N_NODES * 4);
    float*    ew     = (float*)take((size_t)N_EDGES * 4);
    uint_t*   bucket = (uint_t*)take((size_t)N_NODES * CAP * 4);
    ushort_t* xb     = (ushort_t*)take((size_t)NX * 2 + 256);
    ushort_t* g1     = (ushort_t*)take((size_t)N_NODES * HID * 2 + 256);
    ushort_t* g2     = (ushort_t*)take((size_t)N_NODES * HID * 2 + 256);
    ushort_t* g3     = (ushort_t*)take((size_t)N_NODES * HID * 2 + 256);
    ushort_t* curA   = (ushort_t*)take((size_t)N_NODES * HID * 2 + 256);
    ushort_t* curB   = (ushort_t*)take((size_t)N_NODES * HID * 2 + 256);
    ushort_t* Z      = (ushort_t*)take((size_t)N_NODES * 32 * 2 + 256);
    ushort_t* t8a    = (ushort_t*)take((size_t)N_NODES * 8 * 2 + 256);
    ushort_t* t8b    = (ushort_t*)take((size_t)N_NODES * 8 * 2 + 256);

    hipMemsetAsync(cnts, 0, (size_t)N_NODES * 4, stream);

    const int EB = (N_EDGES + 255) / 256;   // 3125

    edge_mlp_kernel<<<EB, 256, 0, stream>>>(ea, x, ei, W1, b1, W2, b2, xb, ew, cnts, bucket);
    degdinv_kernel<<<NWB, 256, 0, stream>>>(cnts, bucket, ew, dinv);
    rescale_kernel<<<NWB, 256, 0, stream>>>(cnts, dinv, ew, ei, bucket);

    // ---- layer 0: 16 -> 64, relu ----
    prop_kernel<NFEAT><<<PPB, 256, 0, stream>>>(xb, g1, cnts, bucket);
    prop_kernel<NFEAT><<<PPB, 256, 0, stream>>>(g1, g2, cnts, bucket);
    prop_kernel<NFEAT><<<PPB, 256, 0, stream>>>(g2, g3, cnts, bucket);
    gemm4_kernel<NFEAT, HID, 1><<<PGB, 256, 0, stream>>>(
        xb, g1, g2, g3, Wf, bf, curA);

    // ---- mid layers: 64 -> 64, relu (ping-pong curA/curB) ----
    ushort_t* cin = curA;
    ushort_t* cot = curB;
    for (int L = 0; L < NMID; ++L) {
        prop_kernel<HID><<<PPB, 256, 0, stream>>>(cin, g1, cnts, bucket);
        prop_kernel<HID><<<PPB, 256, 0, stream>>>(g1, g2, cnts, bucket);
        prop_kernel<HID><<<PPB, 256, 0, stream>>>(g2, g3, cnts, bucket);
        gemm4_kernel<HID, HID, 1><<<PGB, 256, 0, stream>>>(
            cin, g1, g2, g3, Wm + (size_t)L * 4 * HID * HID, bm + L * HID, cot);
        ushort_t* t = cin; cin = cot; cot = t;
    }

    // ---- last layer (Horner): Z = [z0+b|z1|z2|z3]; out = z0 + A(z1 + A(z2 + A z3)) ----
    gemmL_kernel<<<PGB, 256, 0, stream>>>(cin, Wl, bl, Z);
    prop8_kernel<0><<<PPB, 256, 0, stream>>>(Z, 32, 24, Z, 32, 16, t8a, nullptr, cnts, bucket);
    prop8_kernel<0><<<PPB, 256, 0, stream>>>(t8a, 8, 0, Z, 32, 8, t8b, nullptr, cnts, bucket);
    prop8_kernel<1><<<PPB, 256, 0, stream>>>(t8b, 8, 0, Z, 32, 0, nullptr, (float*)d_out, cnts, bucket);
}